// Round 9
// baseline (244.407 us; speedup 1.0000x reference)
//
#include <hip/hip_runtime.h>

#define N1 2048
#define N2 32768
#define DD 1024
#define BM 256
#define BN 256
#define BK 128          // fp8 bytes per K-tile row
#define NBM (N1 / BM)   // 8
#define NBN (N2 / BN)   // 128
#define KT  (DD / BK)   // 8
#define NKEY 2048       // keys per query row = (N2/64) * 4

typedef __attribute__((ext_vector_type(8))) int   i32x8;
typedef __attribute__((ext_vector_type(4))) int   i32x4;
typedef __attribute__((ext_vector_type(4))) float f32x4;

typedef const __attribute__((address_space(1))) void gv_t;
typedef __attribute__((address_space(3))) void       lv_t;

__device__ __forceinline__ void gload16(const void* g, void* l) {
  __builtin_amdgcn_global_load_lds((gv_t*)g, (lv_t*)l, 16, 0, 0);
}

__device__ __forceinline__ unsigned ordf(float x) {  // order-preserving f32->u32
  union { float f; unsigned u; } a; a.f = x;
  return a.u ^ ((unsigned)((int)a.u >> 31) | 0x80000000u);
}

// Row-normalize + convert to fp8 e4m3 (x16 pre-scale; ranking is
// scale-invariant, final rescore is exact fp32).
__global__ __launch_bounds__(256) void nrmcvt8(const float* __restrict__ src,
                                               unsigned char* __restrict__ dst,
                                               float* __restrict__ invn) {
  const int row = blockIdx.x, t = threadIdx.x;
  const float4* s4 = (const float4*)(src + (size_t)row * DD);
  float4 v = s4[t];
  float ss = v.x * v.x + v.y * v.y + v.z * v.z + v.w * v.w;
  #pragma unroll
  for (int o = 32; o > 0; o >>= 1) ss += __shfl_down(ss, o, 64);
  __shared__ float red[4];
  if ((t & 63) == 0) red[t >> 6] = ss;
  __syncthreads();
  float inv = 1.0f / sqrtf(red[0] + red[1] + red[2] + red[3]);
  float sc = inv * 16.0f;
  int p = 0;
  p = __builtin_amdgcn_cvt_pk_fp8_f32(v.x * sc, v.y * sc, p, false);
  p = __builtin_amdgcn_cvt_pk_fp8_f32(v.z * sc, v.w * sc, p, true);
  ((unsigned*)(dst + (size_t)row * DD))[t] = (unsigned)p;
  if (invn != nullptr && t == 0) invn[row] = inv;
}

// 256x256 MX-fp8 GEMM, 8 waves (2Mx4N, 128x64 each), counted-vmcnt 2-phase:
// stage tile t+1 BEFORE computing tile t; wait vmcnt(8) (= tile t's loads,
// issued one kt earlier) — next-tile loads stay in flight across barriers.
// Every LDS fragment read exactly once per kt. Fused strip top-4 epilogue.
__global__ __launch_bounds__(512, 2) void gemm_topk(
    const unsigned char* __restrict__ qb,
    const unsigned char* __restrict__ mbn,
    unsigned* __restrict__ cand_k) {
  __shared__ char lds[131072];  // 2 bufs x (A 32KB + B 32KB); scores union
  const int tid  = threadIdx.x;
  const int lane = tid & 63;
  const int w = tid >> 6, wr = w >> 2, wc = w & 3;

  // XCD-aware bijective swizzle (grid 1024 % 8 == 0)
  int bid = blockIdx.x;
  int swz = (bid & 7) * (NBM * NBN / 8) + (bid >> 3);
  const int bm = swz >> 7;          // NBN == 128
  const int bn = swz & (NBN - 1);

  const char* aG = (const char*)(qb  + (size_t)bm * BM * DD);
  const char* bG = (const char*)(mbn + (size_t)bn * BN * DD);

  f32x4 acc[8][4] = {};

  // Stage A+B tile kt into buffer d (64KB, 8 gload16/thread). Linear LDS
  // dest; XOR swizzle (chunk ^= row&7) applied on GLOBAL source (rule #21).
  auto stage = [&](int d, int kt) {
    #pragma unroll
    for (int it = 0; it < 4; ++it) {
      int p = it * 512 + tid;
      int r = p >> 3, c = p & 7, cs = c ^ (r & 7);
      gload16(aG + (size_t)r * DD + kt * BK + cs * 16,
              lds + d * 65536 + p * 16);
    }
    #pragma unroll
    for (int it = 0; it < 4; ++it) {
      int p = it * 512 + tid;
      int r = p >> 3, c = p & 7, cs = c ^ (r & 7);
      gload16(bG + (size_t)r * DD + kt * BK + cs * 16,
              lds + d * 65536 + 32768 + p * 16);
    }
  };

  auto compute = [&](int d) {
    const char* Abuf = lds + d * 65536;
    const char* Bbuf = Abuf + 32768;
    const int g2 = 2 * (lane >> 4);
    // B fragments once (4 x 2 b128 reads), then stream A (8 x 2 reads),
    // 4 MFMAs per A fragment — every fragment read exactly once.
    i32x8 bb[4];
    #pragma unroll
    for (int j = 0; j < 4; ++j) {
      int rb = wc * 64 + j * 16 + (lane & 15);
      i32x4 blo = *(const i32x4*)(Bbuf + rb * 128 + ((g2 ^ (rb & 7)) * 16));
      i32x4 bhi = *(const i32x4*)(Bbuf + rb * 128 + (((g2 + 1) ^ (rb & 7)) * 16));
      bb[j] = __builtin_shufflevector(blo, bhi, 0, 1, 2, 3, 4, 5, 6, 7);
    }
    #pragma unroll
    for (int i = 0; i < 8; ++i) {
      int ra = wr * 128 + i * 16 + (lane & 15);
      i32x4 lo = *(const i32x4*)(Abuf + ra * 128 + ((g2 ^ (ra & 7)) * 16));
      i32x4 hi = *(const i32x4*)(Abuf + ra * 128 + (((g2 + 1) ^ (ra & 7)) * 16));
      i32x8 af = __builtin_shufflevector(lo, hi, 0, 1, 2, 3, 4, 5, 6, 7);
      #pragma unroll
      for (int j = 0; j < 4; ++j)
        acc[i][j] = __builtin_amdgcn_mfma_scale_f32_16x16x128_f8f6f4(
            af, bb[j], acc[i][j], 0 /*A=e4m3*/, 0 /*B=e4m3*/,
            0, 0x7F7F7F7F, 0, 0x7F7F7F7F /*unit e8m0 scales*/);
    }
  };

  stage(0, 0);
  #pragma unroll 1
  for (int t = 0; t < KT - 1; ++t) {
    __builtin_amdgcn_s_barrier();           // readers of buf[(t+1)&1] done
    stage((t + 1) & 1, t + 1);              // 8 loads -> 16 outstanding
    asm volatile("s_waitcnt vmcnt(8)" ::: "memory");  // tile t landed (mine)
    __builtin_amdgcn_s_barrier();           // tile t landed (all waves)
    __builtin_amdgcn_sched_barrier(0);
    compute(t & 1);
  }
  asm volatile("s_waitcnt vmcnt(0)" ::: "memory");
  __builtin_amdgcn_s_barrier();
  __builtin_amdgcn_sched_barrier(0);
  compute((KT - 1) & 1);
  __syncthreads();

  // ---- epilogue: two 128-row half passes through LDS (R2-verified),
  // strip top-4 as packed (17-bit score | 15-bit index) keys ----
  for (int half = 0; half < 2; ++half) {
    if (wr == half) {
      float* sc = (float*)lds;
      #pragma unroll
      for (int i = 0; i < 8; ++i)
        #pragma unroll
        for (int q = 0; q < 4; ++q) {
          int lr = i * 16 + (lane >> 4) * 4 + q;
          #pragma unroll
          for (int j = 0; j < 4; ++j) {
            int c = wc * 64 + j * 16 + (lane & 15);
            sc[lr * 256 + (c ^ ((lr & 15) << 2))] = acc[i][j][q];
          }
        }
    }
    __syncthreads();
    {
      const float* sc = (const float*)lds;
      const int lr = tid >> 2, st = tid & 3;
      unsigned k0 = 0, k1 = 0, k2 = 0, k3 = 0;
      #pragma unroll
      for (int k4 = 0; k4 < 16; ++k4) {
        int c0 = st * 64 + k4 * 4;
        f32x4 v = *(const f32x4*)(sc + lr * 256 + (c0 ^ ((lr & 15) << 2)));
        #pragma unroll
        for (int e = 0; e < 4; ++e) {
          unsigned key = (ordf(v[e]) & 0xFFFF8000u) |
                         (unsigned)(bn * BN + c0 + e);
          unsigned b = key, t2;
          t2 = k0 < b ? k0 : b; k0 = k0 < b ? b : k0; b = t2;
          t2 = k1 < b ? k1 : b; k1 = k1 < b ? b : k1; b = t2;
          t2 = k2 < b ? k2 : b; k2 = k2 < b ? b : k2; b = t2;
          k3 = k3 < b ? b : k3;
        }
      }
      int qrow = bm * BM + half * 128 + lr;
      unsigned* dst = cand_k + (size_t)qrow * NKEY + (bn * 4 + st) * 4;
      *(uint4*)dst = make_uint4(k0, k1, k2, k3);
    }
    __syncthreads();
  }
}

// One wave per query row: top-16 of 2048 packed keys, exact fp32 rescore,
// stable top-4, gather synth rows and average.
__global__ __launch_bounds__(256) void finalize(
    const float* __restrict__ q, const float* __restrict__ m,
    const float* __restrict__ synth, const unsigned* __restrict__ cand_k,
    const float* __restrict__ inv_mn, float* __restrict__ out) {
  const int lane = threadIdx.x & 63;
  const int row  = blockIdx.x * 4 + (threadIdx.x >> 6);

  uint4 kk[8];
  const uint4* kp = (const uint4*)(cand_k + (size_t)row * NKEY);
  #pragma unroll
  for (int ii = 0; ii < 8; ++ii) kk[ii] = kp[ii * 64 + lane];

  const float4* qp = (const float4*)(q + (size_t)row * DD);
  float4 qv[4];
  #pragma unroll
  for (int ph = 0; ph < 4; ++ph) qv[ph] = qp[ph * 64 + lane];

  unsigned wk[16];
  #pragma unroll
  for (int it = 0; it < 16; ++it) {
    unsigned lm = 0;
    #pragma unroll
    for (int ii = 0; ii < 8; ++ii) {
      unsigned a = kk[ii].x > kk[ii].y ? kk[ii].x : kk[ii].y;
      unsigned b = kk[ii].z > kk[ii].w ? kk[ii].z : kk[ii].w;
      a = a > b ? a : b;
      lm = lm > a ? lm : a;
    }
    #pragma unroll
    for (int o = 1; o < 64; o <<= 1) {
      unsigned other = (unsigned)__shfl_xor((int)lm, o, 64);
      lm = lm > other ? lm : other;
    }
    wk[it] = lm;
    #pragma unroll
    for (int ii = 0; ii < 8; ++ii) {
      kk[ii].x = kk[ii].x == lm ? 0u : kk[ii].x;
      kk[ii].y = kk[ii].y == lm ? 0u : kk[ii].y;
      kk[ii].z = kk[ii].z == lm ? 0u : kk[ii].z;
      kk[ii].w = kk[ii].w == lm ? 0u : kk[ii].w;
    }
  }

  float cosv[16]; int gidx[16];
  #pragma unroll
  for (int it = 0; it < 16; ++it) {
    int g = (int)(wk[it] & 0x7FFFu);
    gidx[it] = g;
    const float4* mp = (const float4*)(m + (size_t)g * DD);
    float d = 0.f;
    #pragma unroll
    for (int ph = 0; ph < 4; ++ph) {
      float4 mv = mp[ph * 64 + lane];
      d += mv.x * qv[ph].x + mv.y * qv[ph].y + mv.z * qv[ph].z + mv.w * qv[ph].w;
    }
    #pragma unroll
    for (int o = 1; o < 64; o <<= 1) d += __shfl_xor(d, o, 64);
    cosv[it] = d * inv_mn[g];
  }

  int sel[4]; bool used[16] = {};
  #pragma unroll
  for (int s = 0; s < 4; ++s) {
    float bv = -1e30f; int bg = 0x7FFFFFFF; int bj = -1;
    #pragma unroll
    for (int j = 0; j < 16; ++j) {
      bool better = !used[j] && (cosv[j] > bv || (cosv[j] == bv && gidx[j] < bg));
      bv = better ? cosv[j] : bv;
      bg = better ? gidx[j] : bg;
      bj = better ? j : bj;
    }
    sel[s] = bg;
    #pragma unroll
    for (int j = 0; j < 16; ++j) used[j] = used[j] || (j == bj);
  }

  const float4* s0 = (const float4*)(synth + (size_t)sel[0] * DD);
  const float4* s1 = (const float4*)(synth + (size_t)sel[1] * DD);
  const float4* s2 = (const float4*)(synth + (size_t)sel[2] * DD);
  const float4* s3 = (const float4*)(synth + (size_t)sel[3] * DD);
  float4* op = (float4*)(out + (size_t)row * DD);
  #pragma unroll
  for (int ph = 0; ph < 4; ++ph) {
    int ix = ph * 64 + lane;
    float4 a = s0[ix], b = s1[ix], c = s2[ix], d = s3[ix];
    float4 r;
    r.x = (a.x + b.x + c.x + d.x) * 0.25f;
    r.y = (a.y + b.y + c.y + d.y) * 0.25f;
    r.z = (a.z + b.z + c.z + d.z) * 0.25f;
    r.w = (a.w + b.w + c.w + d.w) * 0.25f;
    op[ix] = r;
  }
}

extern "C" void kernel_launch(void* const* d_in, const int* in_sizes, int n_in,
                              void* d_out, int out_size, void* d_ws, size_t ws_size,
                              hipStream_t stream) {
  (void)in_sizes; (void)n_in; (void)out_size; (void)ws_size;
  const float* q = (const float*)d_in[0];
  const float* m = (const float*)d_in[1];
  const float* s = (const float*)d_in[2];
  float* out = (float*)d_out;

  // ws layout: qb 2MB | mb 32MB (at 2MB) | inv_mn (at 40MB) | cand_k (at 41MB, 16MB)
  char* w = (char*)d_ws;
  unsigned char* qb     = (unsigned char*)w;
  unsigned char* mb     = (unsigned char*)(w + (2ull << 20));
  float*         inv_mn = (float*)(w + (40ull << 20));
  unsigned*      cand_k = (unsigned*)(w + (41ull << 20));

  nrmcvt8<<<N1, 256, 0, stream>>>(q, qb, nullptr);
  nrmcvt8<<<N2, 256, 0, stream>>>(m, mb, inv_mn);
  gemm_topk<<<NBM * NBN, 512, 0, stream>>>(qb, mb, cand_k);
  finalize<<<N1 / 4, 256, 0, stream>>>(q, m, s, cand_k, inv_mn, out);
}

// Round 10
// 242.152 us; speedup vs baseline: 1.0093x; 1.0093x over previous
//
#include <hip/hip_runtime.h>

#define N1 2048
#define N2 32768
#define DD 1024
#define RS 1028   // padded LDS row stride (floats) in nrmcvtT

typedef __attribute__((ext_vector_type(8))) int   i32x8;
typedef __attribute__((ext_vector_type(4))) int   i32x4;
typedef __attribute__((ext_vector_type(4))) float f32x4;

typedef const __attribute__((address_space(1))) void gv_t;
typedef __attribute__((address_space(3))) void       lv_t;

__device__ __forceinline__ void gload16(const void* g, void* l) {
  __builtin_amdgcn_global_load_lds((gv_t*)g, (lv_t*)l, 16, 0, 0);
}

__device__ __forceinline__ unsigned ordf(float x) {  // order-preserving f32->u32
  union { float f; unsigned u; } a; a.f = x;
  return a.u ^ ((unsigned)((int)a.u >> 31) | 0x80000000u);
}

// Row-normalize + fp8-convert + TRANSPOSE to fragment-major layout.
// Per 16-row group g, per kt: 2KB block where byte (hi*1024 + lane*16 + b)
// holds row (lane&15), k-byte kt*128 + (lane>>4)*32 + hi*16 + b.
// => a wave's MFMA fragment read is two fully-coalesced 1KB loads.
__global__ __launch_bounds__(256) void nrmcvtT(const float* __restrict__ src,
                                               unsigned char* __restrict__ dstT,
                                               float* __restrict__ invn) {
  __shared__ float ldsf[16 * RS];
  __shared__ float invs[16];
  const int t = threadIdx.x, g = blockIdx.x;
  const float4* s4 = (const float4*)(src + (size_t)g * 16 * DD);
  #pragma unroll
  for (int it = 0; it < 16; ++it) {
    int p = it * 256 + t;                 // 0..4095 float4s
    int row = p >> 8, c4 = p & 255;
    *(float4*)(ldsf + row * RS + c4 * 4) = s4[p];
  }
  __syncthreads();
  const int l = t & 63, w = t >> 6;
  #pragma unroll
  for (int rr = 0; rr < 4; ++rr) {
    int row = w * 4 + rr;
    float ss = 0.f;
    #pragma unroll
    for (int it = 0; it < 4; ++it) {
      float4 v = *(const float4*)(ldsf + row * RS + (it * 64 + l) * 4);
      ss += v.x * v.x + v.y * v.y + v.z * v.z + v.w * v.w;
    }
    #pragma unroll
    for (int o = 32; o > 0; o >>= 1) ss += __shfl_down(ss, o, 64);
    if (l == 0) {
      float inv = 1.0f / sqrtf(ss);
      invs[row] = inv;
      if (invn != nullptr) invn[g * 16 + row] = inv;
    }
  }
  __syncthreads();
  unsigned* dst4 = (unsigned*)(dstT + (size_t)g * 16384);
  #pragma unroll
  for (int it = 0; it < 4; ++it) {
    int p = it * 256 + t;                 // 0..1023 16B-units
    int L = p * 16;
    int kt = L >> 11, hi = (L >> 10) & 1, idx = (L >> 4) & 63;
    int qq = idx >> 4, r = idx & 15;
    int k0 = kt * 128 + qq * 32 + hi * 16;
    float sc = invs[r] * 16.0f;           // x16: e4m3 sweet range
    uint4 o;
    unsigned* op = (unsigned*)&o;
    #pragma unroll
    for (int e = 0; e < 4; ++e) {
      float4 v = *(const float4*)(ldsf + r * RS + k0 + e * 4);
      int pk = 0;
      pk = __builtin_amdgcn_cvt_pk_fp8_f32(v.x * sc, v.y * sc, pk, false);
      pk = __builtin_amdgcn_cvt_pk_fp8_f32(v.z * sc, v.w * sc, pk, true);
      op[e] = (unsigned)pk;
    }
    *(uint4*)(dst4 + p * 4) = o;
  }
}

// Barrier-free streaming GEMM: Q-panel (64 rows) in LDS once; B fragments
// stream from transposed global (coalesced, L2-slice-resident per XCD);
// running per-lane-subset top-3 keys in registers; per-strip top-6 merge.
// Each wave independently owns a 64q x 512n strip; no sync in the hot loop.
__global__ __launch_bounds__(256, 2) void gemm_topk(
    const unsigned char* __restrict__ qbT,
    const unsigned char* __restrict__ mbT,
    unsigned* __restrict__ cand) {
  __shared__ char lds[65536];
  const int tid = threadIdx.x, l = tid & 63, w = tid >> 6;
  const int qg = blockIdx.x >> 4;         // 0..31  (64-row q panel)
  const int nb = blockIdx.x & 15;         // 0..15  (nb%8 -> XCD affinity)
  const int n0w = nb * 2048 + w * 512;    // wave's n-strip base

  {  // stage Q-panel: 4 groups x 8 kt x 2KB = 64KB, linear (transposed src)
    const char* src = (const char*)(qbT + (size_t)qg * 65536);
    #pragma unroll
    for (int it = 0; it < 16; ++it) {
      int off = (it * 256 + tid) * 16;
      gload16(src + off, lds + off);
    }
  }
  __syncthreads();

  unsigned keys[16][3];
  #pragma unroll
  for (int s = 0; s < 16; ++s) {
    keys[s][0] = 0; keys[s][1] = 0; keys[s][2] = 0;
  }

  #pragma unroll 1
  for (int nc = 0; nc < 8; ++nc) {        // 8 x 64-col chunks
    f32x4 acc[4][4] = {};
    const char* mB = (const char*)mbT +
                     (size_t)((n0w >> 4) + nc * 4) * 16384;
    #pragma unroll
    for (int kt = 0; kt < 8; ++kt) {
      i32x8 bf[4], af[4];
      #pragma unroll
      for (int j = 0; j < 4; ++j) {
        i32x4 lo = *(const i32x4*)(mB + j * 16384 + kt * 2048 + l * 16);
        i32x4 hi = *(const i32x4*)(mB + j * 16384 + kt * 2048 + 1024 + l * 16);
        bf[j] = __builtin_shufflevector(lo, hi, 0, 1, 2, 3, 4, 5, 6, 7);
      }
      #pragma unroll
      for (int i = 0; i < 4; ++i) {
        i32x4 lo = *(const i32x4*)(lds + (i * 8 + kt) * 2048 + l * 16);
        i32x4 hi = *(const i32x4*)(lds + (i * 8 + kt) * 2048 + 1024 + l * 16);
        af[i] = __builtin_shufflevector(lo, hi, 0, 1, 2, 3, 4, 5, 6, 7);
      }
      #pragma unroll
      for (int i = 0; i < 4; ++i)
        #pragma unroll
        for (int j = 0; j < 4; ++j)
          acc[i][j] = __builtin_amdgcn_mfma_scale_f32_16x16x128_f8f6f4(
              af[i], bf[j], acc[i][j], 0 /*e4m3*/, 0 /*e4m3*/,
              0, 0x7F7F7F7F, 0, 0x7F7F7F7F /*unit e8m0*/);
    }
    // fold chunk scores into running per-(row-slot) top-3 keys
    #pragma unroll
    for (int i = 0; i < 4; ++i)
      #pragma unroll
      for (int j = 0; j < 4; ++j)
        #pragma unroll
        for (int r = 0; r < 4; ++r) {
          unsigned key = (ordf(acc[i][j][r]) & 0xFFFF8000u) |
                         (unsigned)(n0w + nc * 64 + j * 16 + (l & 15));
          const int s = i * 4 + r;
          unsigned b = key, t2;
          t2 = keys[s][0] < b ? keys[s][0] : b;
          keys[s][0] = keys[s][0] < b ? b : keys[s][0]; b = t2;
          t2 = keys[s][1] < b ? keys[s][1] : b;
          keys[s][1] = keys[s][1] < b ? b : keys[s][1]; b = t2;
          keys[s][2] = keys[s][2] < b ? b : keys[s][2];
        }
  }

  // ---- per-(row, wave-strip) merge: 16 lanes x 3 -> top-6 ----
  __syncthreads();                         // Q-panel dead; reuse LDS
  unsigned* ldsu = (unsigned*)lds;         // [4*64 rows][49] padded
  #pragma unroll
  for (int s = 0; s < 16; ++s) {
    int r64 = (s >> 2) * 16 + (l >> 4) * 4 + (s & 3);
    int base = (w * 64 + r64) * 49 + (l & 15) * 3;
    ldsu[base + 0] = keys[s][0];
    ldsu[base + 1] = keys[s][1];
    ldsu[base + 2] = keys[s][2];
  }
  __syncthreads();
  {
    int w2 = tid >> 6, r = tid & 63;
    const unsigned* kp = ldsu + (w2 * 64 + r) * 49;
    unsigned m0 = 0, m1 = 0, m2 = 0, m3 = 0, m4 = 0, m5 = 0;
    #pragma unroll
    for (int k = 0; k < 48; ++k) {
      unsigned b = kp[k], t2;
      t2 = m0 < b ? m0 : b; m0 = m0 < b ? b : m0; b = t2;
      t2 = m1 < b ? m1 : b; m1 = m1 < b ? b : m1; b = t2;
      t2 = m2 < b ? m2 : b; m2 = m2 < b ? b : m2; b = t2;
      t2 = m3 < b ? m3 : b; m3 = m3 < b ? b : m3; b = t2;
      t2 = m4 < b ? m4 : b; m4 = m4 < b ? b : m4; b = t2;
      m5 = m5 < b ? b : m5;
    }
    int row = qg * 64 + r;
    int strip = nb * 4 + w2;
    unsigned* dst = cand + (size_t)row * 384 + strip * 6;
    dst[0] = m0; dst[1] = m1; dst[2] = m2;
    dst[3] = m3; dst[4] = m4; dst[5] = m5;
  }
}

// One wave per query row: top-16 of 384 strip keys, exact fp32 rescore,
// stable top-4, gather synth rows and average.
__global__ __launch_bounds__(256) void finalize(
    const float* __restrict__ q, const float* __restrict__ m,
    const float* __restrict__ synth, const unsigned* __restrict__ cand,
    const float* __restrict__ inv_mn, float* __restrict__ out) {
  const int lane = threadIdx.x & 63;
  const int row  = blockIdx.x * 4 + (threadIdx.x >> 6);

  unsigned kk[6];
  const unsigned* kp = cand + (size_t)row * 384 + lane * 6;
  #pragma unroll
  for (int d = 0; d < 6; ++d) kk[d] = kp[d];

  const float4* qp = (const float4*)(q + (size_t)row * DD);
  float4 qv[4];
  #pragma unroll
  for (int ph = 0; ph < 4; ++ph) qv[ph] = qp[ph * 64 + lane];

  unsigned wk[16];
  #pragma unroll
  for (int it = 0; it < 16; ++it) {
    unsigned lm = 0;
    #pragma unroll
    for (int d = 0; d < 6; ++d) lm = lm > kk[d] ? lm : kk[d];
    #pragma unroll
    for (int o = 1; o < 64; o <<= 1) {
      unsigned other = (unsigned)__shfl_xor((int)lm, o, 64);
      lm = lm > other ? lm : other;
    }
    wk[it] = lm;
    #pragma unroll
    for (int d = 0; d < 6; ++d) kk[d] = (kk[d] == lm) ? 0u : kk[d];
  }

  float cosv[16]; int gidx[16];
  #pragma unroll
  for (int it = 0; it < 16; ++it) {
    int g = (int)(wk[it] & 0x7FFFu);
    gidx[it] = g;
    const float4* mp = (const float4*)(m + (size_t)g * DD);
    float d = 0.f;
    #pragma unroll
    for (int ph = 0; ph < 4; ++ph) {
      float4 mv = mp[ph * 64 + lane];
      d += mv.x * qv[ph].x + mv.y * qv[ph].y + mv.z * qv[ph].z + mv.w * qv[ph].w;
    }
    #pragma unroll
    for (int o = 1; o < 64; o <<= 1) d += __shfl_xor(d, o, 64);
    cosv[it] = d * inv_mn[g];
  }

  int sel[4]; bool used[16] = {};
  #pragma unroll
  for (int s = 0; s < 4; ++s) {
    float bv = -1e30f; int bg = 0x7FFFFFFF; int bj = -1;
    #pragma unroll
    for (int j = 0; j < 16; ++j) {
      bool better = !used[j] && (cosv[j] > bv || (cosv[j] == bv && gidx[j] < bg));
      bv = better ? cosv[j] : bv;
      bg = better ? gidx[j] : bg;
      bj = better ? j : bj;
    }
    sel[s] = bg;
    #pragma unroll
    for (int j = 0; j < 16; ++j) used[j] = used[j] || (j == bj);
  }

  const float4* s0 = (const float4*)(synth + (size_t)sel[0] * DD);
  const float4* s1 = (const float4*)(synth + (size_t)sel[1] * DD);
  const float4* s2 = (const float4*)(synth + (size_t)sel[2] * DD);
  const float4* s3 = (const float4*)(synth + (size_t)sel[3] * DD);
  float4* op = (float4*)(out + (size_t)row * DD);
  #pragma unroll
  for (int ph = 0; ph < 4; ++ph) {
    int ix = ph * 64 + lane;
    float4 a = s0[ix], b = s1[ix], c = s2[ix], d = s3[ix];
    float4 r;
    r.x = (a.x + b.x + c.x + d.x) * 0.25f;
    r.y = (a.y + b.y + c.y + d.y) * 0.25f;
    r.z = (a.z + b.z + c.z + d.z) * 0.25f;
    r.w = (a.w + b.w + c.w + d.w) * 0.25f;
    op[ix] = r;
  }
}

extern "C" void kernel_launch(void* const* d_in, const int* in_sizes, int n_in,
                              void* d_out, int out_size, void* d_ws, size_t ws_size,
                              hipStream_t stream) {
  (void)in_sizes; (void)n_in; (void)out_size; (void)ws_size;
  const float* q = (const float*)d_in[0];
  const float* m = (const float*)d_in[1];
  const float* s = (const float*)d_in[2];
  float* out = (float*)d_out;

  // ws: qbT 2MB @0 | mbT 32MB @4MB | inv_mn @40MB | cand 3.1MB @41MB
  char* wsp = (char*)d_ws;
  unsigned char* qbT    = (unsigned char*)wsp;
  unsigned char* mbT    = (unsigned char*)(wsp + (4ull << 20));
  float*         inv_mn = (float*)(wsp + (40ull << 20));
  unsigned*      cand   = (unsigned*)(wsp + (41ull << 20));

  nrmcvtT<<<N1 / 16, 256, 0, stream>>>(q, qbT, nullptr);
  nrmcvtT<<<N2 / 16, 256, 0, stream>>>(m, mbT, inv_mn);
  gemm_topk<<<(N1 / 64) * (N2 / 2048), 256, 0, stream>>>(qbT, mbT, cand);
  finalize<<<N1 / 4, 256, 0, stream>>>(q, m, s, cand, inv_mn, out);
}

// Round 11
// 238.906 us; speedup vs baseline: 1.0230x; 1.0136x over previous
//
#include <hip/hip_runtime.h>

#define N1 2048
#define N2 32768
#define DD 1024
#define BM 256
#define BN 256
#define BK 128          // fp8 bytes per K-tile row
#define NBM (N1 / BM)   // 8
#define NBN (N2 / BN)   // 128
#define KT  (DD / BK)   // 8
#define NKEY 2048       // keys per query row

typedef __attribute__((ext_vector_type(8))) int   i32x8;
typedef __attribute__((ext_vector_type(4))) int   i32x4;
typedef __attribute__((ext_vector_type(4))) float f32x4;

typedef const __attribute__((address_space(1))) void gv_t;
typedef __attribute__((address_space(3))) void       lv_t;

__device__ __forceinline__ void gload16(const void* g, void* l) {
  __builtin_amdgcn_global_load_lds((gv_t*)g, (lv_t*)l, 16, 0, 0);
}

__device__ __forceinline__ unsigned ordf(float x) {  // order-preserving f32->u32
  union { float f; unsigned u; } a; a.f = x;
  return a.u ^ ((unsigned)((int)a.u >> 31) | 0x80000000u);
}

// Row-normalize + convert to fp8 e4m3 (x16 pre-scale; ranking is
// scale-invariant, final rescore is exact fp32).
__global__ __launch_bounds__(256) void nrmcvt8(const float* __restrict__ src,
                                               unsigned char* __restrict__ dst,
                                               float* __restrict__ invn) {
  const int row = blockIdx.x, t = threadIdx.x;
  const float4* s4 = (const float4*)(src + (size_t)row * DD);
  float4 v = s4[t];
  float ss = v.x * v.x + v.y * v.y + v.z * v.z + v.w * v.w;
  #pragma unroll
  for (int o = 32; o > 0; o >>= 1) ss += __shfl_down(ss, o, 64);
  __shared__ float red[4];
  if ((t & 63) == 0) red[t >> 6] = ss;
  __syncthreads();
  float inv = 1.0f / sqrtf(red[0] + red[1] + red[2] + red[3]);
  float sc = inv * 16.0f;
  int p = 0;
  p = __builtin_amdgcn_cvt_pk_fp8_f32(v.x * sc, v.y * sc, p, false);
  p = __builtin_amdgcn_cvt_pk_fp8_f32(v.z * sc, v.w * sc, p, true);
  ((unsigned*)(dst + (size_t)row * DD))[t] = (unsigned)p;
  if (invn != nullptr && t == 0) invn[row] = inv;
}

// 256x256 MX-fp8 GEMM with R4's PROVEN 2-barrier control flow, scaled:
// 8 waves (2Mx4N, each 128x64), 1 block/CU. LDS traffic per FLOP is 1.48x
// better than the 128^2 tile (65 vs 44 FLOP/LDS-byte). Fused strip top-4.
__global__ __launch_bounds__(512, 2) void gemm_topk(
    const unsigned char* __restrict__ qb,
    const unsigned char* __restrict__ mbn,
    unsigned* __restrict__ cand_k) {
  __shared__ char lds[131072];  // 2 bufs x (A 32KB + B 32KB); scores union
  const int tid  = threadIdx.x;
  const int lane = tid & 63;
  const int w = tid >> 6, wr = w >> 2, wc = w & 3;

  // XCD-aware bijective swizzle (grid 1024 % 8 == 0)
  int bid = blockIdx.x;
  int swz = (bid & 7) * (NBM * NBN / 8) + (bid >> 3);
  const int bm = swz >> 7;          // NBN == 128
  const int bn = swz & (NBN - 1);

  const char* aG = (const char*)(qb  + (size_t)bm * BM * DD);
  const char* bG = (const char*)(mbn + (size_t)bn * BN * DD);

  f32x4 acc[8][4] = {};

  // Stage A+B tile kt into buffer d (64KB, 8 gload16/thread). Linear LDS
  // dest; XOR swizzle (chunk ^= row&7) applied on GLOBAL source (rule #21).
  auto stage = [&](int d, int kt) {
    #pragma unroll
    for (int it = 0; it < 4; ++it) {
      int p = it * 512 + tid;
      int r = p >> 3, c = p & 7, cs = c ^ (r & 7);
      gload16(aG + (size_t)r * DD + kt * BK + cs * 16,
              lds + d * 65536 + p * 16);
    }
    #pragma unroll
    for (int it = 0; it < 4; ++it) {
      int p = it * 512 + tid;
      int r = p >> 3, c = p & 7, cs = c ^ (r & 7);
      gload16(bG + (size_t)r * DD + kt * BK + cs * 16,
              lds + d * 65536 + 32768 + p * 16);
    }
  };

  auto compute = [&](int d) {
    const char* Abuf = lds + d * 65536;
    const char* Bbuf = Abuf + 32768;
    const int g2 = 2 * (lane >> 4);
    // B fragments once (4 x 2 b128), then stream A (8 x 2), 4 MFMA per A
    // fragment — every staged byte read exactly once per consuming wave.
    i32x8 bb[4];
    #pragma unroll
    for (int j = 0; j < 4; ++j) {
      int rb = wc * 64 + j * 16 + (lane & 15);
      i32x4 blo = *(const i32x4*)(Bbuf + rb * 128 + ((g2 ^ (rb & 7)) * 16));
      i32x4 bhi = *(const i32x4*)(Bbuf + rb * 128 + (((g2 + 1) ^ (rb & 7)) * 16));
      bb[j] = __builtin_shufflevector(blo, bhi, 0, 1, 2, 3, 4, 5, 6, 7);
    }
    #pragma unroll
    for (int i = 0; i < 8; ++i) {
      int ra = wr * 128 + i * 16 + (lane & 15);
      i32x4 lo = *(const i32x4*)(Abuf + ra * 128 + ((g2 ^ (ra & 7)) * 16));
      i32x4 hi = *(const i32x4*)(Abuf + ra * 128 + (((g2 + 1) ^ (ra & 7)) * 16));
      i32x8 af = __builtin_shufflevector(lo, hi, 0, 1, 2, 3, 4, 5, 6, 7);
      #pragma unroll
      for (int j = 0; j < 4; ++j)
        acc[i][j] = __builtin_amdgcn_mfma_scale_f32_16x16x128_f8f6f4(
            af, bb[j], acc[i][j], 0 /*A=e4m3*/, 0 /*B=e4m3*/,
            0, 0x7F7F7F7F, 0, 0x7F7F7F7F /*unit e8m0 scales*/);
    }
  };

  // R4's proven 2-phase flow: issue next-tile loads, compute current,
  // one full drain + barrier per tile (__syncthreads).
  stage(0, 0);
  __syncthreads();
  #pragma unroll 1
  for (int t = 0; t < KT; ++t) {
    if (t + 1 < KT) stage((t + 1) & 1, t + 1);
    compute(t & 1);
    __syncthreads();
  }

  // ---- epilogue: two 128-row half passes through LDS (R2/R9-verified),
  // strip top-4 as packed (17-bit score | 15-bit index) keys ----
  for (int half = 0; half < 2; ++half) {
    if (wr == half) {
      float* sc = (float*)lds;
      #pragma unroll
      for (int i = 0; i < 8; ++i)
        #pragma unroll
        for (int q = 0; q < 4; ++q) {
          int lr = i * 16 + (lane >> 4) * 4 + q;
          #pragma unroll
          for (int j = 0; j < 4; ++j) {
            int c = wc * 64 + j * 16 + (lane & 15);
            sc[lr * 256 + (c ^ ((lr & 15) << 2))] = acc[i][j][q];
          }
        }
    }
    __syncthreads();
    {
      const float* sc = (const float*)lds;
      const int lr = tid >> 2, st = tid & 3;
      unsigned k0 = 0, k1 = 0, k2 = 0, k3 = 0;
      #pragma unroll
      for (int k4 = 0; k4 < 16; ++k4) {
        int c0 = st * 64 + k4 * 4;
        f32x4 v = *(const f32x4*)(sc + lr * 256 + (c0 ^ ((lr & 15) << 2)));
        #pragma unroll
        for (int e = 0; e < 4; ++e) {
          unsigned key = (ordf(v[e]) & 0xFFFF8000u) |
                         (unsigned)(bn * BN + c0 + e);
          unsigned b = key, t2;
          t2 = k0 < b ? k0 : b; k0 = k0 < b ? b : k0; b = t2;
          t2 = k1 < b ? k1 : b; k1 = k1 < b ? b : k1; b = t2;
          t2 = k2 < b ? k2 : b; k2 = k2 < b ? b : k2; b = t2;
          k3 = k3 < b ? b : k3;
        }
      }
      int qrow = bm * BM + half * 128 + lr;
      unsigned* dst = cand_k + (size_t)qrow * NKEY + (bn * 4 + st) * 4;
      *(uint4*)dst = make_uint4(k0, k1, k2, k3);
    }
    __syncthreads();
  }
}

// One wave per query row: top-16 of 2048 packed keys, exact fp32 rescore,
// stable top-4, gather synth rows and average. (R1/R2-verified.)
__global__ __launch_bounds__(256) void finalize(
    const float* __restrict__ q, const float* __restrict__ m,
    const float* __restrict__ synth, const unsigned* __restrict__ cand_k,
    const float* __restrict__ inv_mn, float* __restrict__ out) {
  const int lane = threadIdx.x & 63;
  const int row  = blockIdx.x * 4 + (threadIdx.x >> 6);

  uint4 kk[8];
  const uint4* kp = (const uint4*)(cand_k + (size_t)row * NKEY);
  #pragma unroll
  for (int ii = 0; ii < 8; ++ii) kk[ii] = kp[ii * 64 + lane];

  const float4* qp = (const float4*)(q + (size_t)row * DD);
  float4 qv[4];
  #pragma unroll
  for (int ph = 0; ph < 4; ++ph) qv[ph] = qp[ph * 64 + lane];

  unsigned wk[16];
  #pragma unroll
  for (int it = 0; it < 16; ++it) {
    unsigned lm = 0;
    #pragma unroll
    for (int ii = 0; ii < 8; ++ii) {
      unsigned a = kk[ii].x > kk[ii].y ? kk[ii].x : kk[ii].y;
      unsigned b = kk[ii].z > kk[ii].w ? kk[ii].z : kk[ii].w;
      a = a > b ? a : b;
      lm = lm > a ? lm : a;
    }
    #pragma unroll
    for (int o = 1; o < 64; o <<= 1) {
      unsigned other = (unsigned)__shfl_xor((int)lm, o, 64);
      lm = lm > other ? lm : other;
    }
    wk[it] = lm;
    #pragma unroll
    for (int ii = 0; ii < 8; ++ii) {
      kk[ii].x = kk[ii].x == lm ? 0u : kk[ii].x;
      kk[ii].y = kk[ii].y == lm ? 0u : kk[ii].y;
      kk[ii].z = kk[ii].z == lm ? 0u : kk[ii].z;
      kk[ii].w = kk[ii].w == lm ? 0u : kk[ii].w;
    }
  }

  float cosv[16]; int gidx[16];
  #pragma unroll
  for (int it = 0; it < 16; ++it) {
    int g = (int)(wk[it] & 0x7FFFu);
    gidx[it] = g;
    const float4* mp = (const float4*)(m + (size_t)g * DD);
    float d = 0.f;
    #pragma unroll
    for (int ph = 0; ph < 4; ++ph) {
      float4 mv = mp[ph * 64 + lane];
      d += mv.x * qv[ph].x + mv.y * qv[ph].y + mv.z * qv[ph].z + mv.w * qv[ph].w;
    }
    #pragma unroll
    for (int o = 1; o < 64; o <<= 1) d += __shfl_xor(d, o, 64);
    cosv[it] = d * inv_mn[g];
  }

  int sel[4]; bool used[16] = {};
  #pragma unroll
  for (int s = 0; s < 4; ++s) {
    float bv = -1e30f; int bg = 0x7FFFFFFF; int bj = -1;
    #pragma unroll
    for (int j = 0; j < 16; ++j) {
      bool better = !used[j] && (cosv[j] > bv || (cosv[j] == bv && gidx[j] < bg));
      bv = better ? cosv[j] : bv;
      bg = better ? gidx[j] : bg;
      bj = better ? j : bj;
    }
    sel[s] = bg;
    #pragma unroll
    for (int j = 0; j < 16; ++j) used[j] = used[j] || (j == bj);
  }

  const float4* s0 = (const float4*)(synth + (size_t)sel[0] * DD);
  const float4* s1 = (const float4*)(synth + (size_t)sel[1] * DD);
  const float4* s2 = (const float4*)(synth + (size_t)sel[2] * DD);
  const float4* s3 = (const float4*)(synth + (size_t)sel[3] * DD);
  float4* op = (float4*)(out + (size_t)row * DD);
  #pragma unroll
  for (int ph = 0; ph < 4; ++ph) {
    int ix = ph * 64 + lane;
    float4 a = s0[ix], b = s1[ix], c = s2[ix], d = s3[ix];
    float4 r;
    r.x = (a.x + b.x + c.x + d.x) * 0.25f;
    r.y = (a.y + b.y + c.y + d.y) * 0.25f;
    r.z = (a.z + b.z + c.z + d.z) * 0.25f;
    r.w = (a.w + b.w + c.w + d.w) * 0.25f;
    op[ix] = r;
  }
}

extern "C" void kernel_launch(void* const* d_in, const int* in_sizes, int n_in,
                              void* d_out, int out_size, void* d_ws, size_t ws_size,
                              hipStream_t stream) {
  (void)in_sizes; (void)n_in; (void)out_size; (void)ws_size;
  const float* q = (const float*)d_in[0];
  const float* m = (const float*)d_in[1];
  const float* s = (const float*)d_in[2];
  float* out = (float*)d_out;

  // ws layout: qb 2MB | mb 32MB (at 2MB) | inv_mn (at 40MB) | cand_k (at 41MB)
  char* w = (char*)d_ws;
  unsigned char* qb     = (unsigned char*)w;
  unsigned char* mb     = (unsigned char*)(w + (2ull << 20));
  float*         inv_mn = (float*)(w + (40ull << 20));
  unsigned*      cand_k = (unsigned*)(w + (41ull << 20));

  nrmcvt8<<<N1, 256, 0, stream>>>(q, qb, nullptr);
  nrmcvt8<<<N2, 256, 0, stream>>>(m, mb, inv_mn);
  gemm_topk<<<NBM * NBN, 512, 0, stream>>>(qb, mb, cand_k);
  finalize<<<N1 / 4, 256, 0, stream>>>(q, m, s, cand_k, inv_mn, out);
}

// Round 12
// 184.475 us; speedup vs baseline: 1.3249x; 1.2951x over previous
//
#include <hip/hip_runtime.h>

#define N1 2048
#define N2 32768
#define DD 1024
#define BM 128
#define BN 128
#define NBM (N1 / BM)   // 16
#define NBN (N2 / BN)   // 256
#define KT  8
#define RS 1028         // padded LDS row stride (floats) in nrmcvtT

typedef __attribute__((ext_vector_type(8))) int   i32x8;
typedef __attribute__((ext_vector_type(4))) int   i32x4;
typedef __attribute__((ext_vector_type(4))) float f32x4;

typedef const __attribute__((address_space(1))) void gv_t;
typedef __attribute__((address_space(3))) void       lv_t;

__device__ __forceinline__ void gload16(const void* g, void* l) {
  __builtin_amdgcn_global_load_lds((gv_t*)g, (lv_t*)l, 16, 0, 0);
}

__device__ __forceinline__ unsigned ordf(float x) {  // order-preserving f32->u32
  union { float f; unsigned u; } a; a.f = x;
  return a.u ^ ((unsigned)((int)a.u >> 31) | 0x80000000u);
}

// Row-normalize + fp8-convert + TRANSPOSE to fragment-major layout
// (R10-verified). Per 16-row group g, per kt: 2KB block where byte
// (hi*1024 + lane*16 + b) holds row (lane&15), k-byte kt*128+(lane>>4)*32
// + hi*16 + b  =>  a wave's MFMA fragment read is two coalesced 1KB loads.
__global__ __launch_bounds__(256) void nrmcvtT(const float* __restrict__ src,
                                               unsigned char* __restrict__ dstT,
                                               float* __restrict__ invn) {
  __shared__ float ldsf[16 * RS];
  __shared__ float invs[16];
  const int t = threadIdx.x, g = blockIdx.x;
  const float4* s4 = (const float4*)(src + (size_t)g * 16 * DD);
  #pragma unroll
  for (int it = 0; it < 16; ++it) {
    int p = it * 256 + t;                 // 0..4095 float4s
    int row = p >> 8, c4 = p & 255;
    *(float4*)(ldsf + row * RS + c4 * 4) = s4[p];
  }
  __syncthreads();
  const int l = t & 63, w = t >> 6;
  #pragma unroll
  for (int rr = 0; rr < 4; ++rr) {
    int row = w * 4 + rr;
    float ss = 0.f;
    #pragma unroll
    for (int it = 0; it < 4; ++it) {
      float4 v = *(const float4*)(ldsf + row * RS + (it * 64 + l) * 4);
      ss += v.x * v.x + v.y * v.y + v.z * v.z + v.w * v.w;
    }
    #pragma unroll
    for (int o = 32; o > 0; o >>= 1) ss += __shfl_down(ss, o, 64);
    if (l == 0) {
      float inv = 1.0f / sqrtf(ss);
      invs[row] = inv;
      if (invn != nullptr) invn[g * 16 + row] = inv;
    }
  }
  __syncthreads();
  unsigned* dst4 = (unsigned*)(dstT + (size_t)g * 16384);
  #pragma unroll
  for (int it = 0; it < 4; ++it) {
    int p = it * 256 + t;                 // 0..1023 16B-units
    int L = p * 16;
    int kt = L >> 11, hi = (L >> 10) & 1, idx = (L >> 4) & 63;
    int qq = idx >> 4, r = idx & 15;
    int k0 = kt * 128 + qq * 32 + hi * 16;
    float sc = invs[r] * 16.0f;           // x16: e4m3 sweet range
    uint4 o;
    unsigned* op = (unsigned*)&o;
    #pragma unroll
    for (int e = 0; e < 4; ++e) {
      float4 v = *(const float4*)(ldsf + r * RS + k0 + e * 4);
      int pk = 0;
      pk = __builtin_amdgcn_cvt_pk_fp8_f32(v.x * sc, v.y * sc, pk, false);
      pk = __builtin_amdgcn_cvt_pk_fp8_f32(v.z * sc, v.w * sc, pk, true);
      op[e] = (unsigned)pk;
    }
    *(uint4*)(dst4 + p * 4) = o;
  }
}

// 128x128 MX-fp8 GEMM, 4 waves (2x2), SINGLE 32KB buffer -> 4 blocks/CU.
// Fragment-major LDS (linear staging, lane-linear conflict-free reads).
// All latency hiding via cross-block TLP (16 waves/CU). Fused strip top-4.
__global__ __launch_bounds__(256, 4) void gemm_topk(
    const unsigned char* __restrict__ qbT,
    const unsigned char* __restrict__ mbT,
    unsigned* __restrict__ cand_k) {
  __shared__ char lds[32768];             // A 16KB | B 16KB; scores union
  const int tid = threadIdx.x, lane = tid & 63;
  const int w = tid >> 6, wr = w >> 1, wc = w & 1;

  // XCD-aware bijective swizzle (grid 4096 % 8 == 0)
  int bid = blockIdx.x;
  int swz = (bid & 7) * (NBM * NBN / 8) + (bid >> 3);
  const int bm = swz >> 8;                // NBN == 256
  const int bn = swz & (NBN - 1);

  const char* aT = (const char*)(qbT + (size_t)bm * 8 * 16384);
  const char* bT = (const char*)(mbT + (size_t)bn * 8 * 16384);

  f32x4 acc[4][4] = {};

  // Stage tile kt: A 16KB + B 16KB, both LINEAR (src is fragment-major).
  auto stage = [&](int kt) {
    #pragma unroll
    for (int it = 0; it < 4; ++it) {
      int p = it * 256 + tid;             // 0..1023 16B-units
      int gi = p >> 7, off = (p & 127) * 16;
      gload16(aT + (size_t)gi * 16384 + kt * 2048 + off, lds + p * 16);
    }
    #pragma unroll
    for (int it = 0; it < 4; ++it) {
      int p = it * 256 + tid;
      int gi = p >> 7, off = (p & 127) * 16;
      gload16(bT + (size_t)gi * 16384 + kt * 2048 + off,
              lds + 16384 + p * 16);
    }
  };

  auto compute = [&]() {
    i32x8 af[4], bb[4];
    #pragma unroll
    for (int i = 0; i < 4; ++i) {
      const char* ab = lds + (wr * 4 + i) * 2048;
      i32x4 lo  = *(const i32x4*)(ab + lane * 16);
      i32x4 hi  = *(const i32x4*)(ab + 1024 + lane * 16);
      af[i] = __builtin_shufflevector(lo, hi, 0, 1, 2, 3, 4, 5, 6, 7);
      const char* bbf = lds + 16384 + (wc * 4 + i) * 2048;
      i32x4 blo = *(const i32x4*)(bbf + lane * 16);
      i32x4 bhi = *(const i32x4*)(bbf + 1024 + lane * 16);
      bb[i] = __builtin_shufflevector(blo, bhi, 0, 1, 2, 3, 4, 5, 6, 7);
    }
    #pragma unroll
    for (int i = 0; i < 4; ++i)
      #pragma unroll
      for (int j = 0; j < 4; ++j)
        acc[i][j] = __builtin_amdgcn_mfma_scale_f32_16x16x128_f8f6f4(
            af[i], bb[j], acc[i][j], 0 /*A=e4m3*/, 0 /*B=e4m3*/,
            0, 0x7F7F7F7F, 0, 0x7F7F7F7F /*unit e8m0 scales*/);
  };

  #pragma unroll 1
  for (int kt = 0; kt < KT; ++kt) {
    stage(kt);
    __syncthreads();   // vmcnt(0) drain + all waves' loads landed
    compute();
    __syncthreads();   // readers done before next overwrite
  }

  // ---- epilogue: two 64-row half passes (32KB), rotated scalar layout
  // (R1-proven conflict-free), strip top-4 as packed keys ----
  float* sc = (float*)lds;
  for (int half = 0; half < 2; ++half) {
    if (wr == half) {
      #pragma unroll
      for (int i = 0; i < 4; ++i)
        #pragma unroll
        for (int j = 0; j < 4; ++j)
          #pragma unroll
          for (int q = 0; q < 4; ++q) {
            int r = i * 16 + (lane >> 4) * 4 + q;       // local 0..63
            int c = wc * 64 + j * 16 + (lane & 15);
            sc[r * 128 + ((c + r) & 127)] = acc[i][j][q];
          }
    }
    __syncthreads();
    if (tid < 128) {
      const int srow = tid >> 1, strip = tid & 1;
      unsigned k0 = 0, k1 = 0, k2 = 0, k3 = 0;
      for (int i2 = 0; i2 < 64; ++i2) {
        int c = strip * 64 + i2;
        float s = sc[srow * 128 + ((c + srow) & 127)];
        unsigned key = (ordf(s) & 0xFFFF8000u) | (unsigned)(bn * BN + c);
        unsigned b = key, t2;
        t2 = k0 < b ? k0 : b; k0 = k0 < b ? b : k0; b = t2;
        t2 = k1 < b ? k1 : b; k1 = k1 < b ? b : k1; b = t2;
        t2 = k2 < b ? k2 : b; k2 = k2 < b ? b : k2; b = t2;
        k3 = k3 < b ? b : k3;
      }
      int qrow = bm * BM + half * 64 + srow;
      unsigned* dst = cand_k + (size_t)qrow * (NBN * 8) + bn * 8 + strip * 4;
      *(uint4*)dst = make_uint4(k0, k1, k2, k3);
    }
    __syncthreads();
  }
}

// One wave per query row: top-16 of 2048 packed keys, exact fp32 rescore,
// stable top-4, gather synth rows and average. (R1/R4-verified.)
__global__ __launch_bounds__(256) void finalize(
    const float* __restrict__ q, const float* __restrict__ m,
    const float* __restrict__ synth, const unsigned* __restrict__ cand_k,
    const float* __restrict__ inv_mn, float* __restrict__ out) {
  const int lane = threadIdx.x & 63;
  const int row  = blockIdx.x * 4 + (threadIdx.x >> 6);

  uint4 kk[8];
  const uint4* kp = (const uint4*)(cand_k + (size_t)row * (NBN * 8));
  #pragma unroll
  for (int ii = 0; ii < 8; ++ii) kk[ii] = kp[ii * 64 + lane];

  const float4* qp = (const float4*)(q + (size_t)row * DD);
  float4 qv[4];
  #pragma unroll
  for (int ph = 0; ph < 4; ++ph) qv[ph] = qp[ph * 64 + lane];

  unsigned wk[16];
  #pragma unroll
  for (int it = 0; it < 16; ++it) {
    unsigned lm = 0;
    #pragma unroll
    for (int ii = 0; ii < 8; ++ii) {
      unsigned a = kk[ii].x > kk[ii].y ? kk[ii].x : kk[ii].y;
      unsigned b = kk[ii].z > kk[ii].w ? kk[ii].z : kk[ii].w;
      a = a > b ? a : b;
      lm = lm > a ? lm : a;
    }
    #pragma unroll
    for (int o = 1; o < 64; o <<= 1) {
      unsigned other = (unsigned)__shfl_xor((int)lm, o, 64);
      lm = lm > other ? lm : other;
    }
    wk[it] = lm;
    #pragma unroll
    for (int ii = 0; ii < 8; ++ii) {
      kk[ii].x = kk[ii].x == lm ? 0u : kk[ii].x;
      kk[ii].y = kk[ii].y == lm ? 0u : kk[ii].y;
      kk[ii].z = kk[ii].z == lm ? 0u : kk[ii].z;
      kk[ii].w = kk[ii].w == lm ? 0u : kk[ii].w;
    }
  }

  float cosv[16]; int gidx[16];
  #pragma unroll
  for (int it = 0; it < 16; ++it) {
    int g = (int)(wk[it] & 0x7FFFu);
    gidx[it] = g;
    const float4* mp = (const float4*)(m + (size_t)g * DD);
    float d = 0.f;
    #pragma unroll
    for (int ph = 0; ph < 4; ++ph) {
      float4 mv = mp[ph * 64 + lane];
      d += mv.x * qv[ph].x + mv.y * qv[ph].y + mv.z * qv[ph].z + mv.w * qv[ph].w;
    }
    #pragma unroll
    for (int o = 1; o < 64; o <<= 1) d += __shfl_xor(d, o, 64);
    cosv[it] = d * inv_mn[g];
  }

  int sel[4]; bool used[16] = {};
  #pragma unroll
  for (int s = 0; s < 4; ++s) {
    float bv = -1e30f; int bg = 0x7FFFFFFF; int bj = -1;
    #pragma unroll
    for (int j = 0; j < 16; ++j) {
      bool better = !used[j] && (cosv[j] > bv || (cosv[j] == bv && gidx[j] < bg));
      bv = better ? cosv[j] : bv;
      bg = better ? gidx[j] : bg;
      bj = better ? j : bj;
    }
    sel[s] = bg;
    #pragma unroll
    for (int j = 0; j < 16; ++j) used[j] = used[j] || (j == bj);
  }

  const float4* s0 = (const float4*)(synth + (size_t)sel[0] * DD);
  const float4* s1 = (const float4*)(synth + (size_t)sel[1] * DD);
  const float4* s2 = (const float4*)(synth + (size_t)sel[2] * DD);
  const float4* s3 = (const float4*)(synth + (size_t)sel[3] * DD);
  float4* op = (float4*)(out + (size_t)row * DD);
  #pragma unroll
  for (int ph = 0; ph < 4; ++ph) {
    int ix = ph * 64 + lane;
    float4 a = s0[ix], b = s1[ix], c = s2[ix], d = s3[ix];
    float4 r;
    r.x = (a.x + b.x + c.x + d.x) * 0.25f;
    r.y = (a.y + b.y + c.y + d.y) * 0.25f;
    r.z = (a.z + b.z + c.z + d.z) * 0.25f;
    r.w = (a.w + b.w + c.w + d.w) * 0.25f;
    op[ix] = r;
  }
}

extern "C" void kernel_launch(void* const* d_in, const int* in_sizes, int n_in,
                              void* d_out, int out_size, void* d_ws, size_t ws_size,
                              hipStream_t stream) {
  (void)in_sizes; (void)n_in; (void)out_size; (void)ws_size;
  const float* q = (const float*)d_in[0];
  const float* m = (const float*)d_in[1];
  const float* s = (const float*)d_in[2];
  float* out = (float*)d_out;

  // ws: qbT 2MB @0 | mbT 32MB @4MB | inv_mn @40MB | cand_k 16MB @41MB
  char* wsp = (char*)d_ws;
  unsigned char* qbT    = (unsigned char*)wsp;
  unsigned char* mbT    = (unsigned char*)(wsp + (4ull << 20));
  float*         inv_mn = (float*)(wsp + (40ull << 20));
  unsigned*      cand_k = (unsigned*)(wsp + (41ull << 20));

  nrmcvtT<<<N1 / 16, 256, 0, stream>>>(q, qbT, nullptr);
  nrmcvtT<<<N2 / 16, 256, 0, stream>>>(m, mbT, inv_mn);
  gemm_topk<<<NBM * NBN, 256, 0, stream>>>(qbT, mbT, cand_k);
  finalize<<<N1 / 4, 256, 0, stream>>>(q, m, s, cand_k, inv_mn, out);
}